// Round 6
// baseline (4654.662 us; speedup 1.0000x reference)
//
#include <hip/hip_runtime.h>

// Problem constants (fixed by the reference)
#define NN 20000      // nodes
#define EE 240000     // real edges
#define ETOTAL 260000 // edges + self loops
#define DIN 768
#define DD 256
#define NT 9          // tags
// heads = 4, DH = 64

__device__ __forceinline__ unsigned fenc(float x) {
  unsigned u = __float_as_uint(x);
  return (u & 0x80000000u) ? ~u : (u | 0x80000000u);
}
__device__ __forceinline__ float fdec(unsigned e) {
  unsigned u = (e & 0x80000000u) ? (e ^ 0x80000000u) : ~e;
  return __uint_as_float(u);
}
__device__ __forceinline__ float gelu_f(float x) {
  return 0.5f * x * (1.0f + erff(x * 0.70710678118654752440f));
}

// row_ror:r as a source op on a float (bitcast through int)
#define ROR_F(r, v) __int_as_float(__builtin_amdgcn_update_dpp( \
    __float_as_int(v), __float_as_int(v), 0x120 + (r), 0xF, 0xF, false))
// one-time direction probe: source-lane offset of row_ror:r (readlane of dst 0)
#define PROBE_D(r) __builtin_amdgcn_readlane( \
    __builtin_amdgcn_update_dpp(jl, jl, 0x120 + (r), 0xF, 0xF, false), 0)

// ---------------- GEMM: C = act(A@B + bias [+ addc]) ----------------
// A: MxK row-major, B: KxN row-major, C: MxN. Requires N%64==0, K%32==0.
// act: 0 = none, 1 = gelu, 2 = bn(g,b) then relu
// Tile 128x64, 8x4 per thread. A tile row-major [128][33] (+1 pad:
// staging writes <=2-way conflicts, compute reads broadcast conflict-free).
__global__ __launch_bounds__(256) void gemm_k(
    const float* __restrict__ A, const float* __restrict__ B,
    const float* __restrict__ bias, const float* __restrict__ addc,
    const float* __restrict__ bng, const float* __restrict__ bnb,
    float* __restrict__ C, int M, int K, int N, int act)
{
  __shared__ float As[128][33];
  __shared__ float Bs[32][64];
  const int tid = threadIdx.x;
  const int tx = tid & 15;   // col group: 4 cols
  const int ty = tid >> 4;   // row group: 8 rows
  const int m0 = blockIdx.y * 128, n0 = blockIdx.x * 64;
  float acc[8][4];
#pragma unroll
  for (int i = 0; i < 8; ++i)
#pragma unroll
    for (int j = 0; j < 4; ++j) acc[i][j] = 0.f;

  for (int kk = 0; kk < K; kk += 32) {
    // stage A: 128 rows x 8 float4 (4 per thread), coalesced global reads
#pragma unroll
    for (int i = tid; i < 1024; i += 256) {
      int r = i >> 3, c4 = i & 7;
      int gm = m0 + r;
      float4 v = make_float4(0.f, 0.f, 0.f, 0.f);
      if (gm < M) v = *(const float4*)(A + (size_t)gm * K + kk + c4 * 4);
      As[r][c4 * 4 + 0] = v.x; As[r][c4 * 4 + 1] = v.y;
      As[r][c4 * 4 + 2] = v.z; As[r][c4 * 4 + 3] = v.w;
    }
    // stage B: 32 rows x 16 float4 (2 per thread)
#pragma unroll
    for (int i = tid; i < 512; i += 256) {
      int r = i >> 4, c4 = i & 15;
      *(float4*)&Bs[r][c4 * 4] = *(const float4*)(B + (size_t)(kk + r) * N + n0 + c4 * 4);
    }
    __syncthreads();
#pragma unroll
    for (int k = 0; k < 32; ++k) {
      float b[4];
      *(float4*)b = *(const float4*)&Bs[k][tx * 4];
      float a[8];
#pragma unroll
      for (int i = 0; i < 8; ++i) a[i] = As[ty * 8 + i][k];
#pragma unroll
      for (int i = 0; i < 8; ++i)
#pragma unroll
        for (int j = 0; j < 4; ++j) acc[i][j] += a[i] * b[j];
    }
    __syncthreads();
  }
  const float bnc = 0.99999500003749968752f;  // 1/sqrt(1+1e-5)
#pragma unroll
  for (int i = 0; i < 8; ++i) {
    int gm = m0 + ty * 8 + i;
    if (gm >= M) continue;
    float o[4];
#pragma unroll
    for (int j = 0; j < 4; ++j) {
      int n = n0 + tx * 4 + j;
      float x = acc[i][j];
      if (bias) x += bias[n];
      if (addc) x += addc[(size_t)gm * N + n];
      if (act == 1) x = gelu_f(x);
      else if (act == 2) { x = x * (bng[n] * bnc) + bnb[n]; x = fmaxf(x, 0.f); }
      o[j] = x;
    }
    *(float4*)(C + (size_t)gm * N + n0 + tx * 4) = *(const float4*)o;
  }
}

// ---------------- per-layer edge-type tables (9 types) ----------------
__global__ __launch_bounds__(256) void edge_tables_k(
    const float* __restrict__ We1l, const float* __restrict__ be1l,
    const float* __restrict__ g1l, const float* __restrict__ bb1l,
    const float* __restrict__ We2l, const float* __restrict__ be2l,
    const float* __restrict__ WkEl, const float* __restrict__ bkl,
    const float* __restrict__ WmEl, const float* __restrict__ bml,
    float* __restrict__ ketab, float* __restrict__ metab)
{
  __shared__ float r_s[DD];
  __shared__ float e_s[DD];
  const int t = blockIdx.x, d = threadIdx.x;
  const float bnc = 0.99999500003749968752f;
  float pre = We1l[t * DD + d] + be1l[d];
  float bnv = pre * (g1l[d] * bnc) + bb1l[d];
  r_s[d] = fmaxf(bnv, 0.f);
  __syncthreads();
  float acc = 0.f;
  for (int c = 0; c < DD; ++c) acc += r_s[c] * We2l[c * DD + d];
  e_s[d] = acc + be2l[d];
  __syncthreads();
  float ka = 0.f, ma = 0.f;
  for (int c = 0; c < DD; ++c) {
    float ec = e_s[c];
    ka += ec * WkEl[c * DD + d];
    ma += ec * WmEl[c * DD + d];
  }
  ketab[t * DD + d] = ka + bkl[d];
  metab[t * DD + d] = ma + bml[d];
}

// ---------------- degree counts ----------------
__global__ void deg_k(const int* __restrict__ ei, int* __restrict__ cnt,
                      int* __restrict__ cnt_d)
{
  for (int e = blockIdx.x * blockDim.x + threadIdx.x; e < EE; e += gridDim.x * blockDim.x) {
    atomicAdd(&cnt[ei[e]], 1);        // src out-degree (real edges)
    atomicAdd(&cnt_d[ei[EE + e]], 1); // dst in-degree (real edges)
  }
}

// ---------------- exclusive scan over cnt_d (single block) ----------------
__global__ __launch_bounds__(256) void scan_k(const int* __restrict__ c,
                                              int* __restrict__ offs)
{
  __shared__ int part[257];
  const int tid = threadIdx.x;
  const int CH = (NN + 255) / 256;
  int a = tid * CH, b = a + CH; if (b > NN) b = NN;
  int s = 0;
  for (int i = a; i < b; ++i) s += c[i];
  part[tid] = s;
  __syncthreads();
  if (tid == 0) {
    int r = 0;
    for (int i = 0; i < 256; ++i) { int v = part[i]; part[i] = r; r += v; }
    part[256] = r;
  }
  __syncthreads();
  int r = part[tid];
  for (int i = a; i < b; ++i) { offs[i] = r; r += c[i]; }
  if (tid == 255) offs[NN] = part[256];
}

// ---------------- CSR fill (by dst) ----------------
__global__ void fill_k(const int* __restrict__ ei, const int* __restrict__ offs,
                       int* __restrict__ fc, int* __restrict__ eix)
{
  for (int e = blockIdx.x * blockDim.x + threadIdx.x; e < EE; e += gridDim.x * blockDim.x) {
    int d = ei[EE + e];
    int p = offs[d] + atomicAdd(&fc[d], 1);
    eix[p] = e;
  }
}

// ---------------- pass A: attention scores + segment max over src ----------
__global__ __launch_bounds__(256) void score_k(
    const float* __restrict__ Q, const float* __restrict__ Kn,
    const float* __restrict__ ketab, const int* __restrict__ ei,
    const int* __restrict__ et, float* __restrict__ sbuf,
    unsigned* __restrict__ smax)
{
  __shared__ float ke_s[NT * DD];
  for (int i = threadIdx.x; i < NT * DD; i += 256) ke_s[i] = ketab[i];
  __syncthreads();
  const int lane = threadIdx.x & 63, wave = threadIdx.x >> 6;
  const float4* Q4 = (const float4*)Q;
  const float4* K4 = (const float4*)Kn;
  for (int e = blockIdx.x * 4 + wave; e < ETOTAL; e += gridDim.x * 4) {
    int src, dst, t;
    if (e < EE) { src = ei[e]; dst = ei[EE + e]; t = et[e]; }
    else { src = dst = e - EE; t = NT - 1; }
    float4 q = Q4[src * 64 + lane];
    float4 k = K4[dst * 64 + lane];
    float4 ke = *(const float4*)(ke_s + t * DD + lane * 4);
    float p = q.x * (k.x + ke.x) + q.y * (k.y + ke.y) +
              q.z * (k.z + ke.z) + q.w * (k.w + ke.w);
    p += __shfl_xor(p, 8); p += __shfl_xor(p, 4);
    p += __shfl_xor(p, 2); p += __shfl_xor(p, 1);
    if ((lane & 15) == 0) {
      int h = lane >> 4;
      float s = p * 0.125f;            // / sqrt(64)
      sbuf[e * 4 + h] = s;
      atomicMax(smax + src * 4 + h, fenc(s));
    }
  }
}

// ---------------- pass B: exp(s - max) and segment sum over src ------------
__global__ void softmax_k(const int* __restrict__ ei, float* __restrict__ sbuf,
                          const unsigned* __restrict__ smax, float* __restrict__ den)
{
  for (int idx = blockIdx.x * blockDim.x + threadIdx.x; idx < ETOTAL * 4;
       idx += gridDim.x * blockDim.x) {
    int e = idx >> 2, h = idx & 3;
    int src = (e < EE) ? ei[e] : e - EE;
    float s = sbuf[idx];
    float ex = expf(s - fdec(smax[src * 4 + h]));
    sbuf[idx] = ex;
    atomicAdd(den + src * 4 + h, ex);
  }
}

// ---------------- pass C: atomic-free aggregation (wave per dst) -----------
__global__ __launch_bounds__(256) void aggr2_k(
    const float* __restrict__ Mn, const float* __restrict__ metab,
    const int* __restrict__ ei, const int* __restrict__ et,
    const float* __restrict__ sbuf, const float* __restrict__ den,
    const int* __restrict__ cnt, const int* __restrict__ offs,
    const int* __restrict__ eix, float* __restrict__ aggr)
{
  __shared__ float me_s[NT * DD];
  for (int i = threadIdx.x; i < NT * DD; i += 256) me_s[i] = metab[i];
  __syncthreads();
  const int lane = threadIdx.x & 63, wave = threadIdx.x >> 6;
  const int h = lane >> 4;
  const float4* M4 = (const float4*)Mn;
  int dst = blockIdx.x * 4 + wave;
  if (dst >= NN) return;
  float4 acc;
  {
    // self-loop (edge id EE+dst, type NT-1)
    float ex = sbuf[(EE + dst) * 4 + h];
    float dn = den[dst * 4 + h];
    float alpha = ex / (dn + 1e-16f) * (float)(cnt[dst] + 1);
    float4 m = M4[dst * 64 + lane];
    float4 me = *(const float4*)(me_s + (NT - 1) * DD + lane * 4);
    acc.x = (m.x + me.x) * alpha; acc.y = (m.y + me.y) * alpha;
    acc.z = (m.z + me.z) * alpha; acc.w = (m.w + me.w) * alpha;
  }
  int o1 = offs[dst + 1];
  for (int o = offs[dst]; o < o1; ++o) {
    int e = eix[o];
    int src = ei[e], t = et[e];
    float ex = sbuf[e * 4 + h];
    float dn = den[src * 4 + h];
    float alpha = ex / (dn + 1e-16f) * (float)(cnt[src] + 1);
    float4 m = M4[src * 64 + lane];
    float4 me = *(const float4*)(me_s + t * DD + lane * 4);
    acc.x += (m.x + me.x) * alpha; acc.y += (m.y + me.y) * alpha;
    acc.z += (m.z + me.z) * alpha; acc.w += (m.w + me.w) * alpha;
  }
  ((float4*)aggr)[dst * 64 + lane] = acc;
}

// ---------------- emissions: em = hidden @ Wt + bt  (256 -> 9) -------------
__global__ __launch_bounds__(256) void emis_k(
    const float* __restrict__ hidden, const float* __restrict__ Wt,
    const float* __restrict__ bt, float* __restrict__ em)
{
  __shared__ float wt_s[DD * NT];
  for (int i = threadIdx.x; i < DD * NT; i += 256) wt_s[i] = Wt[i];
  __syncthreads();
  const int lane = threadIdx.x & 63, wave = threadIdx.x >> 6;
  const float4* H4 = (const float4*)hidden;
  for (int n = blockIdx.x * 4 + wave; n < NN; n += gridDim.x * 4) {
    float4 h = H4[n * 64 + lane];
    const float* w0 = wt_s + (lane * 4) * NT;
    float p[NT];
#pragma unroll
    for (int t = 0; t < NT; ++t)
      p[t] = h.x * w0[t] + h.y * w0[NT + t] + h.z * w0[2 * NT + t] + h.w * w0[3 * NT + t];
#pragma unroll
    for (int m = 32; m >= 1; m >>= 1)
#pragma unroll
      for (int t = 0; t < NT; ++t) p[t] += __shfl_xor(p[t], m);
    if (lane == 0) {
#pragma unroll
      for (int t = 0; t < NT; ++t) em[n * NT + t] = p[t] + bt[t];
    }
  }
}

// ---------------- Viterbi decode (single block) ----------------------------
// Forward scan on wave0: lane layout = 9 states in lanes 0-8 of each 16-lane
// row (replicated across rows; -inf pad in lanes 9-15). All-pairs candidates
// s_i + T[i][j] via 15 row_ror DPP rotations folded into v_add (no DS ops, no
// readlane on the chain); rotation direction probed at runtime and the masked
// per-rotation tables built accordingly (direction-proof). Max over the 16
// candidates is an exact v_max3 tree -> bitwise identical to the reference
// association (single add, then exact max, then +e). Per-step score row
// stored to sv; backpointers recomputed bitwise-exactly in the parallel
// backtrack (argmax over stored scores, first-index tie rule = jnp.argmax).
__global__ __launch_bounds__(256) void viterbi_k(
    const float* __restrict__ em, const float* __restrict__ cstart,
    const float* __restrict__ cend, const float* __restrict__ ctrans,
    float* __restrict__ sv, int* __restrict__ outp)
{
  const int VCS = 512;
  const int NCH = (NN + VCS - 1) / VCS;
  __shared__ float embuf[2][VCS * NT + 32];   // +pad: compute reads off+2, jl<=15
  __shared__ float trT[NT * 16];              // trT[j*16+i] = trans[i][j]
  __shared__ float scf[NT];
  __shared__ unsigned char fmaps[256][NT];
  __shared__ unsigned char ends_s[256];
  __shared__ int last_s;
  const int tid = threadIdx.x, lane = tid & 63, wave = tid >> 6;
  const int jl = lane & 15;
  const float NINF = -__builtin_inff();

  for (int i = tid; i < VCS * NT; i += 256) embuf[0][i] = em[i];
  if (tid < NT * NT) trT[(tid % NT) * 16 + (tid / NT)] = ctrans[tid];
  __syncthreads();

  float tc[16];
  float s = NINF;
  if (wave == 0) {
    int d[16];
    d[1] = PROBE_D(1);   d[2] = PROBE_D(2);   d[3] = PROBE_D(3);
    d[4] = PROBE_D(4);   d[5] = PROBE_D(5);   d[6] = PROBE_D(6);
    d[7] = PROBE_D(7);   d[8] = PROBE_D(8);   d[9] = PROBE_D(9);
    d[10] = PROBE_D(10); d[11] = PROBE_D(11); d[12] = PROBE_D(12);
    d[13] = PROBE_D(13); d[14] = PROBE_D(14); d[15] = PROBE_D(15);
    tc[0] = (jl < NT) ? ctrans[jl * NT + jl] : NINF;   // self term i=j
#pragma unroll
    for (int r = 1; r < 16; ++r) {
      int i = (jl + d[r]) & 15;    // source lane = source state (if < 9)
      tc[r] = (i < NT && jl < NT) ? ctrans[i * NT + jl] : NINF;
    }
    s = (jl < NT) ? (cstart[jl] + embuf[0][jl]) : NINF;
    sv[jl] = s;                    // row t=0 (cols 9-15 = -inf, unused)
  }

  for (int c = 0; c < NCH; ++c) {
    if (wave > 0) {
      if (c + 1 < NCH) {
        int base = (c + 1) * VCS * NT;
        int n2 = VCS * NT;
        if (base + n2 > NN * NT) n2 = NN * NT - base;
        for (int i = tid - 64; i < n2; i += 192) embuf[(c + 1) & 1][i] = em[base + i];
      }
    } else {
      const float* eb = embuf[c & 1];
      int tbeg = (c == 0) ? 1 : c * VCS;
      int tend = (c + 1) * VCS; if (tend > NN) tend = NN;
      int off = tbeg - c * VCS;
      float e0 = eb[off * NT + jl];          // lanes 9-15: harmless garbage
      float e1 = eb[(off + 1) * NT + jl];
      for (int t = tbeg; t < tend; ++t, ++off) {
        float e2 = eb[(off + 2) * NT + jl];  // pad-safe
        float c0 = s + tc[0];
        float c1 = ROR_F(1, s) + tc[1];
        float c2 = ROR_F(2, s) + tc[2];
        float c3 = ROR_F(3, s) + tc[3];
        float c4 = ROR_F(4, s) + tc[4];
        float c5 = ROR_F(5, s) + tc[5];
        float c6 = ROR_F(6, s) + tc[6];
        float c7 = ROR_F(7, s) + tc[7];
        float c8 = ROR_F(8, s) + tc[8];
        float c9 = ROR_F(9, s) + tc[9];
        float c10 = ROR_F(10, s) + tc[10];
        float c11 = ROR_F(11, s) + tc[11];
        float c12 = ROR_F(12, s) + tc[12];
        float c13 = ROR_F(13, s) + tc[13];
        float c14 = ROR_F(14, s) + tc[14];
        float c15 = ROR_F(15, s) + tc[15];
        float m1 = fmaxf(fmaxf(c0, c1), c2);     // v_max3 tree, exact
        float m2 = fmaxf(fmaxf(c3, c4), c5);
        float m3 = fmaxf(fmaxf(c6, c7), c8);
        float m4 = fmaxf(fmaxf(c9, c10), c11);
        float m5 = fmaxf(fmaxf(c12, c13), c14);
        float ma = fmaxf(fmaxf(m1, m2), m3);
        float mb = fmaxf(fmaxf(m4, m5), c15);
        s = fmaxf(ma, mb) + e0;
        sv[t * 16 + jl] = s;                 // 4-way dup across rows, benign
        e0 = e1; e1 = e2;
      }
    }
    __syncthreads();
  }

  if (wave == 0 && lane < NT) scf[lane] = s + cend[lane];
  __syncthreads();
  if (tid == 0) {
    float bv = scf[0]; int bi = 0;
    for (int j = 1; j < NT; ++j) if (scf[j] > bv) { bv = scf[j]; bi = j; }
    last_s = bi;
  }
  __syncthreads();

  // backtrack: per-range end->start maps via exact bp recomputation
  const int RL = 79;
  int a = 1 + tid * RL;
  int b = a + RL; if (b > NN) b = NN;
  bool active = (a < NN);
  if (active) {
    int x[NT];
#pragma unroll
    for (int j = 0; j < NT; ++j) x[j] = j;
    for (int t = b - 1; t >= a; --t) {
      const float* sp = sv + (size_t)(t - 1) * 16;
      float sr[NT];
#pragma unroll
      for (int i = 0; i < NT; ++i) sr[i] = sp[i];
#pragma unroll
      for (int j = 0; j < NT; ++j) {
        const float* tcx = trT + x[j] * 16;
        float bv = sr[0] + tcx[0]; int bi = 0;
#pragma unroll
        for (int i = 1; i < NT; ++i) {
          float cv = sr[i] + tcx[i];
          if (cv > bv) { bv = cv; bi = i; }
        }
        x[j] = bi;
      }
    }
#pragma unroll
    for (int j = 0; j < NT; ++j) fmaps[tid][j] = (unsigned char)x[j];
  }
  __syncthreads();
  if (tid == 0) {
    int x = last_s;
    for (int k = 255; k >= 0; --k) {
      ends_s[k] = (unsigned char)x;
      int ak = 1 + k * RL;
      if (ak < NN) x = fmaps[k][x];
    }
  }
  __syncthreads();
  if (active) {
    int x = ends_s[tid];
    outp[b - 1] = x;
    for (int t = b - 1; t >= a; --t) {
      const float* sp = sv + (size_t)(t - 1) * 16;
      const float* tcx = trT + x * 16;
      float bv = sp[0] + tcx[0]; int bi = 0;
#pragma unroll
      for (int i = 1; i < NT; ++i) {
        float cv = sp[i] + tcx[i];
        if (cv > bv) { bv = cv; bi = i; }
      }
      x = bi;
      outp[t - 1] = x;
    }
  }
}

// ---------------------------------------------------------------------------
extern "C" void kernel_launch(void* const* d_in, const int* in_sizes, int n_in,
                              void* d_out, int out_size, void* d_ws, size_t ws_size,
                              hipStream_t stream)
{
  const float* node_emb = (const float*)d_in[0];
  const int* edge_index = (const int*)d_in[1];
  const int* edge_type = (const int*)d_in[2];
  // d_in[3] = tag_gt (unused by reference)
  const float* W_lm2gnn = (const float*)d_in[4];
  const float* b_lm2gnn = (const float*)d_in[5];
  const float* We1 = (const float*)d_in[6];
  const float* be1 = (const float*)d_in[7];
  const float* g1 = (const float*)d_in[8];
  const float* bb1 = (const float*)d_in[9];
  const float* We2 = (const float*)d_in[10];
  const float* be2 = (const float*)d_in[11];
  const float* Wq = (const float*)d_in[12];
  const float* bq = (const float*)d_in[13];
  const float* Wk = (const float*)d_in[14];
  const float* bk = (const float*)d_in[15];
  const float* Wm = (const float*)d_in[16];
  const float* bm = (const float*)d_in[17];
  const float* Wp1 = (const float*)d_in[18];
  const float* bp1 = (const float*)d_in[19];
  const float* g2 = (const float*)d_in[20];
  const float* bb2 = (const float*)d_in[21];
  const float* Wp2 = (const float*)d_in[22];
  const float* bp2 = (const float*)d_in[23];
  const float* Wo = (const float*)d_in[24];
  const float* bo = (const float*)d_in[25];
  const float* Wc = (const float*)d_in[26];
  const float* bc = (const float*)d_in[27];
  const float* Wt = (const float*)d_in[28];
  const float* bt = (const float*)d_in[29];
  const float* cstart = (const float*)d_in[30];
  const float* cend = (const float*)d_in[31];
  const float* ctrans = (const float*)d_in[32];

  // Workspace layout: 4 big node buffers + small region.
  const size_t NB = (size_t)NN * DD * sizeof(float); // 20,480,000
  char* w = (char*)d_ws;
  float* H0 = (float*)(w + 0 * NB);
  float* Xb = (float*)(w + 1 * NB);
  float* Qb = (float*)(w + 2 * NB);   // Q, then M, then Xl, then hidden
  float* Kb = (float*)(w + 3 * NB);   // K, then aggr, then H0@Wo tmp
  char* sm = w + 4 * NB;
  size_t smo = 0;
  auto alloc = [&](size_t bytes) { char* p = sm + smo; smo += (bytes + 255) & ~255ull; return p; };
  float* sbuf = (float*)alloc((size_t)ETOTAL * 4 * 4);
  unsigned* smax = (unsigned*)alloc((size_t)NN * 4 * 4);   // contiguous with den
  float* den = (float*)alloc((size_t)NN * 4 * 4);
  int* cnt = (int*)alloc((size_t)NN * 4);                  // cnt..fc zeroed together
  int* cnt_d = (int*)alloc((size_t)NN * 4);
  int* offs = (int*)alloc((size_t)(NN + 1) * 4);
  int* fc = (int*)alloc((size_t)NN * 4);
  int* eix = (int*)alloc((size_t)EE * 4);
  float* ketab = (float*)alloc((size_t)NT * DD * 4);
  float* metab = (float*)alloc((size_t)NT * DD * 4);
  float* em = (float*)alloc((size_t)NN * NT * 4);
  float* sv = (float*)alloc(((size_t)NN * 16 + 16) * 4);
  const size_t needed = 4 * NB + smo;
  if (ws_size < needed) return;  // fail visibly rather than corrupt

  dim3 gg(DD / 64, (NN + 127) / 128);

  // degree counts + dst-CSR (edge structure constant across layers)
  hipMemsetAsync(cnt, 0, (size_t)((char*)eix - (char*)cnt), stream); // cnt,cnt_d,offs,fc
  deg_k<<<1024, 256, 0, stream>>>(edge_index, cnt, cnt_d);
  scan_k<<<1, 256, 0, stream>>>(cnt_d, offs);
  fill_k<<<1024, 256, 0, stream>>>(edge_index, offs, fc, eix);

  // H0 = gelu(node_emb @ W_lm2gnn + b)
  gemm_k<<<gg, 256, 0, stream>>>(node_emb, W_lm2gnn, b_lm2gnn, nullptr, nullptr,
                                 nullptr, H0, NN, DIN, DD, 1);

  const float* Xcur = H0;
  for (int l = 0; l < 3; ++l) {
    edge_tables_k<<<NT, 256, 0, stream>>>(
        We1 + (size_t)l * NT * DD, be1 + l * DD, g1 + l * DD, bb1 + l * DD,
        We2 + (size_t)l * DD * DD, be2 + l * DD,
        Wk + (size_t)l * 2 * DD * DD + DD * DD, bk + l * DD,
        Wm + (size_t)l * 2 * DD * DD + DD * DD, bm + l * DD, ketab, metab);

    gemm_k<<<gg, 256, 0, stream>>>(Xcur, Wq + (size_t)l * DD * DD, bq + l * DD,
                                   nullptr, nullptr, nullptr, Qb, NN, DD, DD, 0);
    gemm_k<<<gg, 256, 0, stream>>>(Xcur, Wk + (size_t)l * 2 * DD * DD, nullptr,
                                   nullptr, nullptr, nullptr, Kb, NN, DD, DD, 0);

    hipMemsetAsync(smax, 0, (size_t)NN * 4 * 4 * 2, stream);  // smax + den
    score_k<<<2048, 256, 0, stream>>>(Qb, Kb, ketab, edge_index, edge_type, sbuf, smax);
    softmax_k<<<2048, 256, 0, stream>>>(edge_index, sbuf, smax, den);

    // M projection into Qb (Q dead after score_k)
    gemm_k<<<gg, 256, 0, stream>>>(Xcur, Wm + (size_t)l * 2 * DD * DD, nullptr,
                                   nullptr, nullptr, nullptr, Qb, NN, DD, DD, 0);
    // aggregate into Kb (K dead after score_k)
    aggr2_k<<<(NN + 3) / 4, 256, 0, stream>>>(Qb, metab, edge_index, edge_type,
                                              sbuf, den, cnt, offs, eix, Kb);

    // Xl = relu(bn(aggr@Wp1 + bp1)); X = gelu(Xl@Wp2 + bp2)
    gemm_k<<<gg, 256, 0, stream>>>(Kb, Wp1 + (size_t)l * DD * DD, bp1 + l * DD,
                                   nullptr, g2 + l * DD, bb2 + l * DD, Qb, NN, DD, DD, 2);
    gemm_k<<<gg, 256, 0, stream>>>(Qb, Wp2 + (size_t)l * DD * DD, bp2 + l * DD,
                                   nullptr, nullptr, nullptr, Xb, NN, DD, DD, 1);
    Xcur = Xb;
  }

  // hidden = gelu(H0@Wo + bo + X@Wc + bc)
  gemm_k<<<gg, 256, 0, stream>>>(H0, Wo, bo, nullptr, nullptr, nullptr, Kb, NN, DD, DD, 0);
  gemm_k<<<gg, 256, 0, stream>>>(Xb, Wc, bc, Kb, nullptr, nullptr, Qb, NN, DD, DD, 1);

  emis_k<<<1250, 256, 0, stream>>>(Qb, Wt, bt, em);
  viterbi_k<<<1, 256, 0, stream>>>(em, cstart, cend, ctrans, sv, (int*)d_out);
}

// Round 7
// 3311.394 us; speedup vs baseline: 1.4057x; 1.4057x over previous
//
#include <hip/hip_runtime.h>

// Problem constants (fixed by the reference)
#define NN 20000      // nodes
#define EE 240000     // real edges
#define ETOTAL 260000 // edges + self loops
#define DIN 768
#define DD 256
#define NT 9          // tags
// heads = 4, DH = 64

__device__ __forceinline__ unsigned fenc(float x) {
  unsigned u = __float_as_uint(x);
  return (u & 0x80000000u) ? ~u : (u | 0x80000000u);
}
__device__ __forceinline__ float fdec(unsigned e) {
  unsigned u = (e & 0x80000000u) ? (e ^ 0x80000000u) : ~e;
  return __uint_as_float(u);
}
__device__ __forceinline__ float gelu_f(float x) {
  return 0.5f * x * (1.0f + erff(x * 0.70710678118654752440f));
}
__device__ __forceinline__ float rdlane(float v, int l) {
  return __int_as_float(__builtin_amdgcn_readlane(__float_as_int(v), l));
}

// ---------------- GEMM: C = act(A@B + bias [+ addc]) ----------------
// A: MxK row-major, B: KxN row-major, C: MxN. Requires N%64==0, K%32==0.
// act: 0 = none, 1 = gelu, 2 = bn(g,b) then relu
// 64x64 tile, 4x4/thread (measured best of {64x64, 128x64} on this shape).
__global__ __launch_bounds__(256) void gemm_k(
    const float* __restrict__ A, const float* __restrict__ B,
    const float* __restrict__ bias, const float* __restrict__ addc,
    const float* __restrict__ bng, const float* __restrict__ bnb,
    float* __restrict__ C, int M, int K, int N, int act)
{
  __shared__ float As[32][64];   // transposed A tile: As[k][m]
  __shared__ float Bs[32][64];   // Bs[k][n]
  const int tid = threadIdx.x;
  const int tx = tid & 15, ty = tid >> 4;
  const int m0 = blockIdx.y * 64, n0 = blockIdx.x * 64;
  float acc[4][4];
#pragma unroll
  for (int i = 0; i < 4; ++i)
#pragma unroll
    for (int j = 0; j < 4; ++j) acc[i][j] = 0.f;

  for (int kk = 0; kk < K; kk += 32) {
#pragma unroll
    for (int L = tid; L < 512; L += 256) {   // A tile: 64 rows x 8 float4
      int r = L >> 3, c4 = L & 7;
      int gm = m0 + r;
      float4 v = make_float4(0.f, 0.f, 0.f, 0.f);
      if (gm < M) v = *(const float4*)(A + (size_t)gm * K + kk + c4 * 4);
      As[c4 * 4 + 0][r] = v.x; As[c4 * 4 + 1][r] = v.y;
      As[c4 * 4 + 2][r] = v.z; As[c4 * 4 + 3][r] = v.w;
    }
#pragma unroll
    for (int L = tid; L < 512; L += 256) {   // B tile: 32 rows x 16 float4
      int r = L >> 4, c4 = L & 15;
      *(float4*)&Bs[r][c4 * 4] = *(const float4*)(B + (size_t)(kk + r) * N + n0 + c4 * 4);
    }
    __syncthreads();
#pragma unroll
    for (int k = 0; k < 32; ++k) {
      float a[4], b[4];
      *(float4*)a = *(const float4*)&As[k][ty * 4];
      *(float4*)b = *(const float4*)&Bs[k][tx * 4];
#pragma unroll
      for (int i = 0; i < 4; ++i)
#pragma unroll
        for (int j = 0; j < 4; ++j) acc[i][j] += a[i] * b[j];
    }
    __syncthreads();
  }
  const float bnc = 0.99999500003749968752f;  // 1/sqrt(1+1e-5)
#pragma unroll
  for (int i = 0; i < 4; ++i) {
    int gm = m0 + ty * 4 + i;
    if (gm >= M) continue;
    float o[4];
#pragma unroll
    for (int j = 0; j < 4; ++j) {
      int n = n0 + tx * 4 + j;
      float x = acc[i][j];
      if (bias) x += bias[n];
      if (addc) x += addc[(size_t)gm * N + n];
      if (act == 1) x = gelu_f(x);
      else if (act == 2) { x = x * (bng[n] * bnc) + bnb[n]; x = fmaxf(x, 0.f); }
      o[j] = x;
    }
    *(float4*)(C + (size_t)gm * N + n0 + tx * 4) = *(const float4*)o;
  }
}

// ---------------- per-layer edge-type tables (9 types) ----------------
__global__ __launch_bounds__(256) void edge_tables_k(
    const float* __restrict__ We1l, const float* __restrict__ be1l,
    const float* __restrict__ g1l, const float* __restrict__ bb1l,
    const float* __restrict__ We2l, const float* __restrict__ be2l,
    const float* __restrict__ WkEl, const float* __restrict__ bkl,
    const float* __restrict__ WmEl, const float* __restrict__ bml,
    float* __restrict__ ketab, float* __restrict__ metab)
{
  __shared__ float r_s[DD];
  __shared__ float e_s[DD];
  const int t = blockIdx.x, d = threadIdx.x;
  const float bnc = 0.99999500003749968752f;
  float pre = We1l[t * DD + d] + be1l[d];
  float bnv = pre * (g1l[d] * bnc) + bb1l[d];
  r_s[d] = fmaxf(bnv, 0.f);
  __syncthreads();
  float acc = 0.f;
  for (int c = 0; c < DD; ++c) acc += r_s[c] * We2l[c * DD + d];
  e_s[d] = acc + be2l[d];
  __syncthreads();
  float ka = 0.f, ma = 0.f;
  for (int c = 0; c < DD; ++c) {
    float ec = e_s[c];
    ka += ec * WkEl[c * DD + d];
    ma += ec * WmEl[c * DD + d];
  }
  ketab[t * DD + d] = ka + bkl[d];
  metab[t * DD + d] = ma + bml[d];
}

// ---------------- degree counts ----------------
__global__ void deg_k(const int* __restrict__ ei, int* __restrict__ cnt,
                      int* __restrict__ cnt_d)
{
  for (int e = blockIdx.x * blockDim.x + threadIdx.x; e < EE; e += gridDim.x * blockDim.x) {
    atomicAdd(&cnt[ei[e]], 1);        // src out-degree (real edges)
    atomicAdd(&cnt_d[ei[EE + e]], 1); // dst in-degree (real edges)
  }
}

// ---------------- exclusive scan over cnt_d (single block) ----------------
__global__ __launch_bounds__(256) void scan_k(const int* __restrict__ c,
                                              int* __restrict__ offs)
{
  __shared__ int part[257];
  const int tid = threadIdx.x;
  const int CH = (NN + 255) / 256;
  int a = tid * CH, b = a + CH; if (b > NN) b = NN;
  int s = 0;
  for (int i = a; i < b; ++i) s += c[i];
  part[tid] = s;
  __syncthreads();
  if (tid == 0) {
    int r = 0;
    for (int i = 0; i < 256; ++i) { int v = part[i]; part[i] = r; r += v; }
    part[256] = r;
  }
  __syncthreads();
  int r = part[tid];
  for (int i = a; i < b; ++i) { offs[i] = r; r += c[i]; }
  if (tid == 255) offs[NN] = part[256];
}

// ---------------- CSR fill (by dst) ----------------
__global__ void fill_k(const int* __restrict__ ei, const int* __restrict__ offs,
                       int* __restrict__ fc, int* __restrict__ eix)
{
  for (int e = blockIdx.x * blockDim.x + threadIdx.x; e < EE; e += gridDim.x * blockDim.x) {
    int d = ei[EE + e];
    int p = offs[d] + atomicAdd(&fc[d], 1);
    eix[p] = e;
  }
}

// ---------------- pass A: attention scores + segment max over src ----------
__global__ __launch_bounds__(256) void score_k(
    const float* __restrict__ Q, const float* __restrict__ Kn,
    const float* __restrict__ ketab, const int* __restrict__ ei,
    const int* __restrict__ et, float* __restrict__ sbuf,
    unsigned* __restrict__ smax)
{
  __shared__ float ke_s[NT * DD];
  for (int i = threadIdx.x; i < NT * DD; i += 256) ke_s[i] = ketab[i];
  __syncthreads();
  const int lane = threadIdx.x & 63, wave = threadIdx.x >> 6;
  const float4* Q4 = (const float4*)Q;
  const float4* K4 = (const float4*)Kn;
  for (int e = blockIdx.x * 4 + wave; e < ETOTAL; e += gridDim.x * 4) {
    int src, dst, t;
    if (e < EE) { src = ei[e]; dst = ei[EE + e]; t = et[e]; }
    else { src = dst = e - EE; t = NT - 1; }
    float4 q = Q4[src * 64 + lane];
    float4 k = K4[dst * 64 + lane];
    float4 ke = *(const float4*)(ke_s + t * DD + lane * 4);
    float p = q.x * (k.x + ke.x) + q.y * (k.y + ke.y) +
              q.z * (k.z + ke.z) + q.w * (k.w + ke.w);
    p += __shfl_xor(p, 8); p += __shfl_xor(p, 4);
    p += __shfl_xor(p, 2); p += __shfl_xor(p, 1);
    if ((lane & 15) == 0) {
      int h = lane >> 4;
      float s = p * 0.125f;            // / sqrt(64)
      sbuf[e * 4 + h] = s;
      atomicMax(smax + src * 4 + h, fenc(s));
    }
  }
}

// ---------------- pass B: exp(s - max) and segment sum over src ------------
__global__ void softmax_k(const int* __restrict__ ei, float* __restrict__ sbuf,
                          const unsigned* __restrict__ smax, float* __restrict__ den)
{
  for (int idx = blockIdx.x * blockDim.x + threadIdx.x; idx < ETOTAL * 4;
       idx += gridDim.x * blockDim.x) {
    int e = idx >> 2, h = idx & 3;
    int src = (e < EE) ? ei[e] : e - EE;
    float s = sbuf[idx];
    float ex = expf(s - fdec(smax[src * 4 + h]));
    sbuf[idx] = ex;
    atomicAdd(den + src * 4 + h, ex);
  }
}

// ---------------- pass C: atomic-free aggregation (wave per dst) -----------
__global__ __launch_bounds__(256) void aggr2_k(
    const float* __restrict__ Mn, const float* __restrict__ metab,
    const int* __restrict__ ei, const int* __restrict__ et,
    const float* __restrict__ sbuf, const float* __restrict__ den,
    const int* __restrict__ cnt, const int* __restrict__ offs,
    const int* __restrict__ eix, float* __restrict__ aggr)
{
  __shared__ float me_s[NT * DD];
  for (int i = threadIdx.x; i < NT * DD; i += 256) me_s[i] = metab[i];
  __syncthreads();
  const int lane = threadIdx.x & 63, wave = threadIdx.x >> 6;
  const int h = lane >> 4;
  const float4* M4 = (const float4*)Mn;
  int dst = blockIdx.x * 4 + wave;
  if (dst >= NN) return;
  float4 acc;
  {
    // self-loop (edge id EE+dst, type NT-1)
    float ex = sbuf[(EE + dst) * 4 + h];
    float dn = den[dst * 4 + h];
    float alpha = ex / (dn + 1e-16f) * (float)(cnt[dst] + 1);
    float4 m = M4[dst * 64 + lane];
    float4 me = *(const float4*)(me_s + (NT - 1) * DD + lane * 4);
    acc.x = (m.x + me.x) * alpha; acc.y = (m.y + me.y) * alpha;
    acc.z = (m.z + me.z) * alpha; acc.w = (m.w + me.w) * alpha;
  }
  int o1 = offs[dst + 1];
  for (int o = offs[dst]; o < o1; ++o) {
    int e = eix[o];
    int src = ei[e], t = et[e];
    float ex = sbuf[e * 4 + h];
    float dn = den[src * 4 + h];
    float alpha = ex / (dn + 1e-16f) * (float)(cnt[src] + 1);
    float4 m = M4[src * 64 + lane];
    float4 me = *(const float4*)(me_s + t * DD + lane * 4);
    acc.x += (m.x + me.x) * alpha; acc.y += (m.y + me.y) * alpha;
    acc.z += (m.z + me.z) * alpha; acc.w += (m.w + me.w) * alpha;
  }
  ((float4*)aggr)[dst * 64 + lane] = acc;
}

// ---------------- emissions: em = hidden @ Wt + bt  (256 -> 9) -------------
__global__ __launch_bounds__(256) void emis_k(
    const float* __restrict__ hidden, const float* __restrict__ Wt,
    const float* __restrict__ bt, float* __restrict__ em)
{
  __shared__ float wt_s[DD * NT];
  for (int i = threadIdx.x; i < DD * NT; i += 256) wt_s[i] = Wt[i];
  __syncthreads();
  const int lane = threadIdx.x & 63, wave = threadIdx.x >> 6;
  const float4* H4 = (const float4*)hidden;
  for (int n = blockIdx.x * 4 + wave; n < NN; n += gridDim.x * 4) {
    float4 h = H4[n * 64 + lane];
    const float* w0 = wt_s + (lane * 4) * NT;
    float p[NT];
#pragma unroll
    for (int t = 0; t < NT; ++t)
      p[t] = h.x * w0[t] + h.y * w0[NT + t] + h.z * w0[2 * NT + t] + h.w * w0[3 * NT + t];
#pragma unroll
    for (int m = 32; m >= 1; m >>= 1)
#pragma unroll
      for (int t = 0; t < NT; ++t) p[t] += __shfl_xor(p[t], m);
    if (lane == 0) {
#pragma unroll
      for (int t = 0; t < NT; ++t) em[n * NT + t] = p[t] + bt[t];
    }
  }
}

// ---------------- Viterbi decode (single block) ----------------------------
// Forward scan: wave0, lanes replicate states j=min(lane&15,8). Score vector
// broadcast via v_readlane (measured best: 204 cyc/step vs bpermute 244,
// DPP 319). This round: v_max3-shaped tree (depth 2, exactly associative ->
// bitwise identical) and score rows stored at stride 64 (distinct address
// per lane -> no same-address write serialization). Backpointers recomputed
// bitwise-exactly in the parallel backtrack (first-index tie rule).
__global__ __launch_bounds__(256) void viterbi_k(
    const float* __restrict__ em, const float* __restrict__ cstart,
    const float* __restrict__ cend, const float* __restrict__ ctrans,
    float* __restrict__ sv, int* __restrict__ outp)
{
  const int VCS = 512;
  const int NCH = (NN + VCS - 1) / VCS;
  __shared__ float embuf[2][VCS * NT + 32];   // +pad: compute reads off+2
  __shared__ float trT[NT * 16];              // trT[j*16+i] = trans[i][j]
  __shared__ float scf[NT];
  __shared__ unsigned char fmaps[256][NT];
  __shared__ unsigned char ends_s[256];
  __shared__ int last_s;
  const int tid = threadIdx.x, lane = tid & 63, wave = tid >> 6;
  const int jl = min(lane & 15, NT - 1);

  for (int i = tid; i < VCS * NT; i += 256) embuf[0][i] = em[i];
  if (tid < NT * NT) trT[(tid % NT) * 16 + (tid / NT)] = ctrans[tid];
  __syncthreads();

  float tcol[NT];   // tcol[i] = trans[i][jl]
  float s = 0.f;
  if (wave == 0) {
#pragma unroll
    for (int i = 0; i < NT; ++i) tcol[i] = ctrans[i * NT + jl];
    s = cstart[jl] + embuf[0][jl];
    sv[lane] = s;                 // row t=0, stride 64
  }

  for (int c = 0; c < NCH; ++c) {
    if (wave > 0) {
      if (c + 1 < NCH) {
        int base = (c + 1) * VCS * NT;
        int n2 = VCS * NT;
        if (base + n2 > NN * NT) n2 = NN * NT - base;
        for (int i = tid - 64; i < n2; i += 192) embuf[(c + 1) & 1][i] = em[base + i];
      }
    } else {
      const float* eb = embuf[c & 1];
      int tbeg = (c == 0) ? 1 : c * VCS;
      int tend = (c + 1) * VCS; if (tend > NN) tend = NN;
      int off = tbeg - c * VCS;
      float* svp = sv + (size_t)tbeg * 64 + lane;
      float e0 = eb[off * NT + jl];
      float e1 = eb[(off + 1) * NT + jl];
      for (int t = tbeg; t < tend; ++t, ++off) {
        float e2 = eb[(off + 2) * NT + jl];   // pad-safe
        float s0 = rdlane(s, 0), s1 = rdlane(s, 1), s2 = rdlane(s, 2);
        float s3 = rdlane(s, 3), s4 = rdlane(s, 4), s5 = rdlane(s, 5);
        float s6 = rdlane(s, 6), s7 = rdlane(s, 7), s8 = rdlane(s, 8);
        float c0 = s0 + tcol[0], c1 = s1 + tcol[1], c2 = s2 + tcol[2];
        float c3 = s3 + tcol[3], c4 = s4 + tcol[4], c5 = s5 + tcol[5];
        float c6 = s6 + tcol[6], c7 = s7 + tcol[7], c8 = s8 + tcol[8];
        float m1 = fmaxf(fmaxf(c0, c1), c2);   // v_max3 x4, depth 2
        float m2 = fmaxf(fmaxf(c3, c4), c5);
        float m3 = fmaxf(fmaxf(c6, c7), c8);
        s = fmaxf(fmaxf(m1, m2), m3) + e0;
        *svp = s; svp += 64;
        e0 = e1; e1 = e2;
      }
    }
    __syncthreads();
  }

  if (wave == 0 && lane < NT) scf[lane] = s + cend[lane];
  __syncthreads();
  if (tid == 0) {
    float bv = scf[0]; int bi = 0;
    for (int j = 1; j < NT; ++j) if (scf[j] > bv) { bv = scf[j]; bi = j; }
    last_s = bi;
  }
  __syncthreads();

  // backtrack: per-range end->start maps via exact bp recomputation
  const int RL = 79;
  int a = 1 + tid * RL;
  int b = a + RL; if (b > NN) b = NN;
  bool active = (a < NN);
  if (active) {
    int x[NT];
#pragma unroll
    for (int j = 0; j < NT; ++j) x[j] = j;
    for (int t = b - 1; t >= a; --t) {
      const float* sp = sv + (size_t)(t - 1) * 64;
      float sr[NT];
#pragma unroll
      for (int i = 0; i < NT; ++i) sr[i] = sp[i];
#pragma unroll
      for (int j = 0; j < NT; ++j) {
        const float* tcx = trT + x[j] * 16;
        float bv = sr[0] + tcx[0]; int bi = 0;
#pragma unroll
        for (int i = 1; i < NT; ++i) {
          float cv = sr[i] + tcx[i];
          if (cv > bv) { bv = cv; bi = i; }
        }
        x[j] = bi;
      }
    }
#pragma unroll
    for (int j = 0; j < NT; ++j) fmaps[tid][j] = (unsigned char)x[j];
  }
  __syncthreads();
  if (tid == 0) {
    int x = last_s;
    for (int k = 255; k >= 0; --k) {
      ends_s[k] = (unsigned char)x;
      int ak = 1 + k * RL;
      if (ak < NN) x = fmaps[k][x];
    }
  }
  __syncthreads();
  if (active) {
    int x = ends_s[tid];
    outp[b - 1] = x;
    for (int t = b - 1; t >= a; --t) {
      const float* sp = sv + (size_t)(t - 1) * 64;
      const float* tcx = trT + x * 16;
      float bv = sp[0] + tcx[0]; int bi = 0;
#pragma unroll
      for (int i = 1; i < NT; ++i) {
        float cv = sp[i] + tcx[i];
        if (cv > bv) { bv = cv; bi = i; }
      }
      x = bi;
      outp[t - 1] = x;
    }
  }
}

// ---------------------------------------------------------------------------
extern "C" void kernel_launch(void* const* d_in, const int* in_sizes, int n_in,
                              void* d_out, int out_size, void* d_ws, size_t ws_size,
                              hipStream_t stream)
{
  const float* node_emb = (const float*)d_in[0];
  const int* edge_index = (const int*)d_in[1];
  const int* edge_type = (const int*)d_in[2];
  // d_in[3] = tag_gt (unused by reference)
  const float* W_lm2gnn = (const float*)d_in[4];
  const float* b_lm2gnn = (const float*)d_in[5];
  const float* We1 = (const float*)d_in[6];
  const float* be1 = (const float*)d_in[7];
  const float* g1 = (const float*)d_in[8];
  const float* bb1 = (const float*)d_in[9];
  const float* We2 = (const float*)d_in[10];
  const float* be2 = (const float*)d_in[11];
  const float* Wq = (const float*)d_in[12];
  const float* bq = (const float*)d_in[13];
  const float* Wk = (const float*)d_in[14];
  const float* bk = (const float*)d_in[15];
  const float* Wm = (const float*)d_in[16];
  const float* bm = (const float*)d_in[17];
  const float* Wp1 = (const float*)d_in[18];
  const float* bp1 = (const float*)d_in[19];
  const float* g2 = (const float*)d_in[20];
  const float* bb2 = (const float*)d_in[21];
  const float* Wp2 = (const float*)d_in[22];
  const float* bp2 = (const float*)d_in[23];
  const float* Wo = (const float*)d_in[24];
  const float* bo = (const float*)d_in[25];
  const float* Wc = (const float*)d_in[26];
  const float* bc = (const float*)d_in[27];
  const float* Wt = (const float*)d_in[28];
  const float* bt = (const float*)d_in[29];
  const float* cstart = (const float*)d_in[30];
  const float* cend = (const float*)d_in[31];
  const float* ctrans = (const float*)d_in[32];

  // Workspace layout: 4 big node buffers + small region.
  const size_t NB = (size_t)NN * DD * sizeof(float); // 20,480,000
  char* w = (char*)d_ws;
  float* H0 = (float*)(w + 0 * NB);
  float* Xb = (float*)(w + 1 * NB);
  float* Qb = (float*)(w + 2 * NB);   // Q, then M, then Xl, then hidden
  float* Kb = (float*)(w + 3 * NB);   // K, then aggr, then H0@Wo tmp
  char* sm = w + 4 * NB;
  size_t smo = 0;
  auto alloc = [&](size_t bytes) { char* p = sm + smo; smo += (bytes + 255) & ~255ull; return p; };
  float* sbuf = (float*)alloc((size_t)ETOTAL * 4 * 4);
  unsigned* smax = (unsigned*)alloc((size_t)NN * 4 * 4);   // contiguous with den
  float* den = (float*)alloc((size_t)NN * 4 * 4);
  int* cnt = (int*)alloc((size_t)NN * 4);                  // cnt..fc zeroed together
  int* cnt_d = (int*)alloc((size_t)NN * 4);
  int* offs = (int*)alloc((size_t)(NN + 1) * 4);
  int* fc = (int*)alloc((size_t)NN * 4);
  int* eix = (int*)alloc((size_t)EE * 4);
  float* ketab = (float*)alloc((size_t)NT * DD * 4);
  float* metab = (float*)alloc((size_t)NT * DD * 4);
  float* em = (float*)alloc((size_t)NN * NT * 4);
  float* sv = (float*)alloc(((size_t)NN * 64 + 64) * 4);   // stride-64 score rows
  const size_t needed = 4 * NB + smo;
  if (ws_size < needed) return;  // fail visibly rather than corrupt

  dim3 gg(DD / 64, (NN + 63) / 64);

  // degree counts + dst-CSR (edge structure constant across layers)
  hipMemsetAsync(cnt, 0, (size_t)((char*)eix - (char*)cnt), stream); // cnt,cnt_d,offs,fc
  deg_k<<<1024, 256, 0, stream>>>(edge_index, cnt, cnt_d);
  scan_k<<<1, 256, 0, stream>>>(cnt_d, offs);
  fill_k<<<1024, 256, 0, stream>>>(edge_index, offs, fc, eix);

  // H0 = gelu(node_emb @ W_lm2gnn + b)
  gemm_k<<<gg, 256, 0, stream>>>(node_emb, W_lm2gnn, b_lm2gnn, nullptr, nullptr,
                                 nullptr, H0, NN, DIN, DD, 1);

  const float* Xcur = H0;
  for (int l = 0; l < 3; ++l) {
    edge_tables_k<<<NT, 256, 0, stream>>>(
        We1 + (size_t)l * NT * DD, be1 + l * DD, g1 + l * DD, bb1 + l * DD,
        We2 + (size_t)l * DD * DD, be2 + l * DD,
        Wk + (size_t)l * 2 * DD * DD + DD * DD, bk + l * DD,
        Wm + (size_t)l * 2 * DD * DD + DD * DD, bm + l * DD, ketab, metab);

    gemm_k<<<gg, 256, 0, stream>>>(Xcur, Wq + (size_t)l * DD * DD, bq + l * DD,
                                   nullptr, nullptr, nullptr, Qb, NN, DD, DD, 0);
    gemm_k<<<gg, 256, 0, stream>>>(Xcur, Wk + (size_t)l * 2 * DD * DD, nullptr,
                                   nullptr, nullptr, nullptr, Kb, NN, DD, DD, 0);

    hipMemsetAsync(smax, 0, (size_t)NN * 4 * 4 * 2, stream);  // smax + den
    score_k<<<2048, 256, 0, stream>>>(Qb, Kb, ketab, edge_index, edge_type, sbuf, smax);
    softmax_k<<<2048, 256, 0, stream>>>(edge_index, sbuf, smax, den);

    // M projection into Qb (Q dead after score_k)
    gemm_k<<<gg, 256, 0, stream>>>(Xcur, Wm + (size_t)l * 2 * DD * DD, nullptr,
                                   nullptr, nullptr, nullptr, Qb, NN, DD, DD, 0);
    // aggregate into Kb (K dead after score_k)
    aggr2_k<<<(NN + 3) / 4, 256, 0, stream>>>(Qb, metab, edge_index, edge_type,
                                              sbuf, den, cnt, offs, eix, Kb);

    // Xl = relu(bn(aggr@Wp1 + bp1)); X = gelu(Xl@Wp2 + bp2)
    gemm_k<<<gg, 256, 0, stream>>>(Kb, Wp1 + (size_t)l * DD * DD, bp1 + l * DD,
                                   nullptr, g2 + l * DD, bb2 + l * DD, Qb, NN, DD, DD, 2);
    gemm_k<<<gg, 256, 0, stream>>>(Qb, Wp2 + (size_t)l * DD * DD, bp2 + l * DD,
                                   nullptr, nullptr, nullptr, Xb, NN, DD, DD, 1);
    Xcur = Xb;
  }

  // hidden = gelu(H0@Wo + bo + X@Wc + bc)
  gemm_k<<<gg, 256, 0, stream>>>(H0, Wo, bo, nullptr, nullptr, nullptr, Kb, NN, DD, DD, 0);
  gemm_k<<<gg, 256, 0, stream>>>(Xb, Wc, bc, Kb, nullptr, nullptr, Qb, NN, DD, DD, 1);

  emis_k<<<1250, 256, 0, stream>>>(Qb, Wt, bt, em);
  viterbi_k<<<1, 256, 0, stream>>>(em, cstart, cend, ctrans, sv, (int*)d_out);
}